// Round 8
// baseline (403.772 us; speedup 1.0000x reference)
//
#include <hip/hip_runtime.h>
#include <cstdint>
#include <cstddef>

// ---------------- common types / helpers ----------------
typedef __bf16 bf16x8 __attribute__((ext_vector_type(8)));
typedef __bf16 bf16x4 __attribute__((ext_vector_type(4)));
typedef float  f32x4  __attribute__((ext_vector_type(4)));
typedef float  f32x16 __attribute__((ext_vector_type(16)));

__device__ __forceinline__ void load16_to_lds(const void* g, void* l) {
  __builtin_amdgcn_global_load_lds(
      (const __attribute__((address_space(1))) void*)g,
      (__attribute__((address_space(3))) void*)l, 16, 0, 0);
}

// ---------------- weight cast+transpose: f32 (K,N) -> bf16 (N,K) ----------------
__global__ __launch_bounds__(256) void transpose_cast(
    const float* __restrict__ src, __bf16* __restrict__ dst, int K, int N)
{
  __shared__ float tile[32][33];
  const int n0 = blockIdx.x * 32, k0 = blockIdx.y * 32;
  const int tx = threadIdx.x, ty = threadIdx.y; // (32,8)
#pragma unroll
  for (int i = 0; i < 32; i += 8)
    tile[ty + i][tx] = src[(size_t)(k0 + ty + i) * N + n0 + tx];
  __syncthreads();
#pragma unroll
  for (int i = 0; i < 32; i += 8)
    dst[(size_t)(n0 + ty + i) * K + k0 + tx] = (__bf16)tile[tx][ty + i];
}

// 3x 1024x1024 in one launch (z picks the weight)
__global__ __launch_bounds__(256) void transpose_cast_qkv(
    const float* __restrict__ s0, const float* __restrict__ s1,
    const float* __restrict__ s2, __bf16* __restrict__ dst)
{
  __shared__ float tile[32][33];
  const float* src = blockIdx.z == 0 ? s0 : blockIdx.z == 1 ? s1 : s2;
  __bf16* d = dst + (size_t)blockIdx.z * 1024 * 1024;
  const int n0 = blockIdx.x * 32, k0 = blockIdx.y * 32;
  const int tx = threadIdx.x, ty = threadIdx.y; // (32,8)
#pragma unroll
  for (int i = 0; i < 32; i += 8)
    tile[ty + i][tx] = src[(size_t)(k0 + ty + i) * 1024 + n0 + tx];
  __syncthreads();
#pragma unroll
  for (int i = 0; i < 32; i += 8)
    d[(size_t)(n0 + ty + i) * 1024 + k0 + tx] = (__bf16)tile[tx][ty + i];
}

// ---------------- LayerNorm: f32 row(1024) -> bf16 ----------------
__global__ __launch_bounds__(256) void ln_kernel(
    const float* __restrict__ x, const float* __restrict__ g,
    const float* __restrict__ bta, __bf16* __restrict__ out)
{
  const int row = blockIdx.x;
  const int t = threadIdx.x;
  const float4 v = ((const float4*)(x + (size_t)row * 1024))[t];
  float s  = v.x + v.y + v.z + v.w;
  float ss = v.x * v.x + v.y * v.y + v.z * v.z + v.w * v.w;
#pragma unroll
  for (int o = 32; o > 0; o >>= 1) { s += __shfl_down(s, o); ss += __shfl_down(ss, o); }
  __shared__ float rs[4], rss[4];
  const int w = t >> 6, l = t & 63;
  if (l == 0) { rs[w] = s; rss[w] = ss; }
  __syncthreads();
  s  = rs[0] + rs[1] + rs[2] + rs[3];
  ss = rss[0] + rss[1] + rss[2] + rss[3];
  const float mu = s * (1.0f / 1024.0f);
  const float var = ss * (1.0f / 1024.0f) - mu * mu;
  const float rstd = rsqrtf(var + 1e-5f);
  const float4 gg = ((const float4*)g)[t];
  const float4 bb = ((const float4*)bta)[t];
  __bf16* o = out + (size_t)row * 1024 + t * 4;
  o[0] = (__bf16)((v.x - mu) * rstd * gg.x + bb.x);
  o[1] = (__bf16)((v.y - mu) * rstd * gg.y + bb.y);
  o[2] = (__bf16)((v.z - mu) * rstd * gg.z + bb.z);
  o[3] = (__bf16)((v.w - mu) * rstd * gg.w + bb.w);
}

// ---------------- bf16 MFMA GEMM: C = A(MxK) * Bt(NxK)^T ----------------
// Double-buffered, ONE barrier per K-iter, PREFETCH-FIRST: the prefetch for
// tile kt+1 is issued right after the barrier (before the ds_reads), so it
// gets a full iteration of flight before the next barrier's vmcnt(0) drain.
// Round-7 version issued it after the frag reads -> only ~MFMA-time flight,
// most of the ~200-900cy load latency still hit the barrier.
enum { EPI_BF16 = 0, EPI_RES_F32 = 1, EPI_GELU_BF16 = 2, EPI_BIAS_RES_F32 = 3 };

template <int TM, int EPI>
__global__ __launch_bounds__(256, 2) void gemm_bf16(
    const __bf16* __restrict__ A, const __bf16* __restrict__ Bt,
    __bf16* __restrict__ outb, float* __restrict__ outf,
    const float* __restrict__ bias, const float* __restrict__ res,
    int M, int N, int K)
{
  constexpr int MT = TM / 32;           // mt tiles per wave
  __shared__ __bf16 As[2][TM * 32];
  __shared__ __bf16 Bs[2][128 * 32];
  const int tid  = threadIdx.x;
  const int lane = tid & 63, w = tid >> 6;
  const int wm = w >> 1, wn = w & 1;
  const int quad = lane >> 4, l16 = lane & 15;
  const int m0 = blockIdx.y * TM, n0 = blockIdx.x * 128;

  f32x4 acc[MT][4] = {};
  const __bf16* Ag = A  + (size_t)m0 * K;
  const __bf16* Bg = Bt + (size_t)n0 * K;

  // prologue: stage tile 0 into buffer 0
#pragma unroll
  for (int r = 0; r < TM / 64; ++r) {
    const int c = r * 256 + tid;
    const int row = c >> 2, cc = (c & 3) * 8;
    load16_to_lds(Ag + (size_t)row * K + cc, &As[0][c * 8]);
  }
#pragma unroll
  for (int r = 0; r < 2; ++r) {
    const int c = r * 256 + tid;
    const int row = c >> 2, cc = (c & 3) * 8;
    load16_to_lds(Bg + (size_t)row * K + cc, &Bs[0][c * 8]);
  }

  const int nk = K >> 5;
  for (int kt = 0; kt < nk; ++kt) {
    __syncthreads();               // drains prefetch for tile kt
    const int p = kt & 1;

    if (kt + 1 < nk) {             // prefetch FIRST: full-iter flight
      const int k1 = (kt + 1) * 32;
#pragma unroll
      for (int r = 0; r < TM / 64; ++r) {
        const int c = r * 256 + tid;
        const int row = c >> 2, cc = (c & 3) * 8;
        load16_to_lds(Ag + (size_t)row * K + k1 + cc, &As[1 - p][c * 8]);
      }
#pragma unroll
      for (int r = 0; r < 2; ++r) {
        const int c = r * 256 + tid;
        const int row = c >> 2, cc = (c & 3) * 8;
        load16_to_lds(Bg + (size_t)row * K + k1 + cc, &Bs[1 - p][c * 8]);
      }
    }

    bf16x8 af[MT], bfr[4];
#pragma unroll
    for (int mt = 0; mt < MT; ++mt)
      af[mt] = *(const bf16x8*)&As[p][(wm * (TM / 2) + mt * 16 + l16) * 32 + quad * 8];
#pragma unroll
    for (int nt = 0; nt < 4; ++nt)
      bfr[nt] = *(const bf16x8*)&Bs[p][(wn * 64 + nt * 16 + l16) * 32 + quad * 8];

#pragma unroll
    for (int mt = 0; mt < MT; ++mt)
#pragma unroll
      for (int nt = 0; nt < 4; ++nt)
        acc[mt][nt] = __builtin_amdgcn_mfma_f32_16x16x32_bf16(af[mt], bfr[nt], acc[mt][nt], 0, 0, 0);
  }

#pragma unroll
  for (int mt = 0; mt < MT; ++mt) {
#pragma unroll
    for (int nt = 0; nt < 4; ++nt) {
      const int col = n0 + wn * 64 + nt * 16 + l16;
#pragma unroll
      for (int i = 0; i < 4; ++i) {
        const int row = m0 + wm * (TM / 2) + mt * 16 + quad * 4 + i;
        float v = acc[mt][nt][i];
        const size_t idx = (size_t)row * N + col;
        if (EPI == EPI_BF16) {
          outb[idx] = (__bf16)v;
        } else if (EPI == EPI_RES_F32) {
          outf[idx] = v + res[idx];
        } else if (EPI == EPI_GELU_BF16) {
          v += bias[col];
          outb[idx] = (__bf16)(0.5f * v * (1.0f + erff(v * 0.70710678118f)));
        } else {
          v += bias[col];
          outf[idx] = v + res[idx];
        }
      }
    }
  }
}

// ---------------- RoPE for q,k: qkv(4096x3072) -> qr,kr [b][h][s][d] --------
// Q is pre-scaled by 0.125*log2(e) so attention scores come out in the exp2
// domain: softmax then needs only sub+v_exp per element (no per-element muls).
__global__ __launch_bounds__(256) void rope_qk(
    const __bf16* __restrict__ qkv, __bf16* __restrict__ qr, __bf16* __restrict__ kr)
{
  const int idx = blockIdx.x * 256 + threadIdx.x; // (b,s,h,d2)
  const int d2 = idx & 31;
  const int h  = (idx >> 5) & 15;
  const int bs = idx >> 9;       // b*2048+s
  const int s  = bs & 2047;
  const int b  = bs >> 11;
  const float inv_freq = exp2f(-((float)d2 * (1.0f / 32.0f)) * 13.2877123795f); // log2(1e4)
  const float ang = (float)s * inv_freq;
  const float c = cosf(ang), sn = sinf(ang);
  const float QS = 0.125f * 1.44269504f;  // (1/sqrt(64)) * log2(e)
  const __bf16* qp = qkv + (size_t)bs * 3072 + h * 64 + 2 * d2;
  const __bf16* kp = qp + 1024;
  const float q0 = (float)qp[0], q1 = (float)qp[1];
  const float k0 = (float)kp[0], k1 = (float)kp[1];
  const size_t o = ((size_t)(b * 16 + h) * 2048 + s) * 64 + 2 * d2;
  qr[o]     = (__bf16)((q0 * c - q1 * sn) * QS);
  qr[o + 1] = (__bf16)((q1 * c + q0 * sn) * QS);
  kr[o]     = (__bf16)(k0 * c - k1 * sn);
  kr[o + 1] = (__bf16)(k1 * c + k0 * sn);
}

// ---------------- V transpose: qkv v-cols -> vt [b][h][d][s] ----------------
__global__ __launch_bounds__(256) void v_transpose(
    const __bf16* __restrict__ qkv, __bf16* __restrict__ vt)
{
  __shared__ __bf16 t[64][72];
  const int st = blockIdx.x, h = blockIdx.y, b = blockIdx.z;
  const int tx = threadIdx.x & 63, ty = threadIdx.x >> 6; // 64x4
  const int s0 = st * 64;
  const __bf16* src = qkv + ((size_t)(b * 2048 + s0)) * 3072 + 2048 + h * 64;
#pragma unroll
  for (int i = 0; i < 64; i += 4)
    t[ty + i][tx] = src[(size_t)(ty + i) * 3072 + tx];
  __syncthreads();
  __bf16* dst = vt + ((size_t)(b * 16 + h) * 64) * 2048 + s0;
#pragma unroll
  for (int i = 0; i < 64; i += 4)
    dst[(size_t)(ty + i) * 2048 + tx] = t[tx][ty + i];
}

// ---------------- flash attention v4: 32x32x16, S^T, exp2-domain softmax ----
// v3 + (a) prefetch issued FIRST after the barrier (full-iter flight before
// the vmcnt(0) drain), (b) scores arrive pre-scaled by 1/8*log2e via Q, so
// softmax is exp2f (bare v_exp) with no per-element multiplies.
__global__ __launch_bounds__(256, 2) void attn_kernel(
    const __bf16* __restrict__ qr, const __bf16* __restrict__ kr,
    const __bf16* __restrict__ vt, __bf16* __restrict__ attn_o)
{
  constexpr int S = 2048, DH = 64, NH = 16, BQ = 128, BKK = 64;
  __shared__ __align__(16) __bf16 smem[24576];  // 48 KB
  __bf16* Qs   = smem;                       // [128][64] swizzled; -> per-wave Pb
  __bf16* Ksb  = smem + 8192;                // 2 x [64][64] swizzled
  __bf16* Vtsb = smem + 16384;               // 2 x [64][64] swizzled

  const int tid = threadIdx.x;
  const int lane = tid & 63, w = tid >> 6;
  const int l32 = lane & 31, half = lane >> 5;
  const int qt = blockIdx.x, h = blockIdx.y, b = blockIdx.z;
  const int bh = b * NH + h;
  const __bf16* Q  = qr + ((size_t)bh * S + qt * BQ) * DH;
  const __bf16* Kp = kr + (size_t)bh * S * DH;
  const __bf16* Vp = vt + (size_t)bh * DH * S;
  __bf16* Pb = Qs + w * 2048;                // wave-local [32][64] swizzled

#pragma unroll
  for (int r4 = 0; r4 < 4; ++r4) {
    const int c = r4 * 256 + tid;
    const int r = c >> 3, cb = c & 7;
    load16_to_lds(Q + (size_t)r * DH + ((cb ^ (r & 7)) * 8), &Qs[c * 8]);
  }
#pragma unroll
  for (int r2 = 0; r2 < 2; ++r2) {
    const int c = r2 * 256 + tid;
    const int r = c >> 3, cb = c & 7;
    const int cg = (cb ^ (r & 7)) * 8;
    load16_to_lds(Kp + (size_t)r * DH + cg, &Ksb[c * 8]);
    load16_to_lds(Vp + (size_t)r * S + cg, &Vtsb[c * 8]);
  }
  __syncthreads();

  bf16x8 qfB[4];
  {
    const int row = w * 32 + l32;
#pragma unroll
    for (int c = 0; c < 4; ++c)
      qfB[c] = *(const bf16x8*)&Qs[row * 64 + (((2 * c + half) ^ (row & 7)) * 8)];
  }

  float mreg = -3.0e38f, lreg = 0.0f;
  f32x16 oacc[2] = {};

  for (int kt = 0; kt < S / BKK; ++kt) {
    if (kt) __syncthreads();

    // prefetch FIRST (full-iteration flight before next barrier's drain)
    if (kt + 1 < S / BKK) {
      __bf16* Kn = Ksb  + ((kt + 1) & 1) * 4096;
      __bf16* Vn = Vtsb + ((kt + 1) & 1) * 4096;
      const size_t kk1 = (size_t)(kt + 1) * BKK;
#pragma unroll
      for (int r2 = 0; r2 < 2; ++r2) {
        const int c = r2 * 256 + tid;
        const int r = c >> 3, cb = c & 7;
        const int cg = (cb ^ (r & 7)) * 8;
        load16_to_lds(Kp + (kk1 + r) * DH + cg, &Kn[c * 8]);
        load16_to_lds(Vp + (size_t)r * S + kk1 + cg, &Vn[c * 8]);
      }
    }

    const __bf16* Ks  = Ksb  + (kt & 1) * 4096;
    const __bf16* Vts = Vtsb + (kt & 1) * 4096;

    bf16x8 kf[2][4], vf[2][4];
#pragma unroll
    for (int t = 0; t < 2; ++t) {
      const int row = 32 * t + l32;
#pragma unroll
      for (int c = 0; c < 4; ++c)
        kf[t][c] = *(const bf16x8*)&Ks[row * 64 + (((2 * c + half) ^ (l32 & 7)) * 8)];
    }
#pragma unroll
    for (int v = 0; v < 2; ++v) {
      const int row = 32 * v + l32;
#pragma unroll
      for (int c = 0; c < 4; ++c)
        vf[v][c] = *(const bf16x8*)&Vts[row * 64 + (((2 * c + half) ^ (l32 & 7)) * 8)];
    }

    // S'^T = K (Q*log2e/8)^T  -- scores already in exp2 domain
    f32x16 sa[2] = {};
#pragma unroll
    for (int t = 0; t < 2; ++t)
#pragma unroll
      for (int c = 0; c < 4; ++c)
        sa[t] = __builtin_amdgcn_mfma_f32_32x32x16_bf16(kf[t][c], qfB[c], sa[t], 0, 0, 0);

    float mx = -3.0e38f;
#pragma unroll
    for (int t = 0; t < 2; ++t)
#pragma unroll
      for (int r = 0; r < 16; ++r) mx = fmaxf(mx, sa[t][r]);
    mx = fmaxf(mx, __shfl_xor(mx, 32));
    const float mnew = fmaxf(mreg, mx);
    const float alpha = exp2f(mreg - mnew);
    mreg = mnew;
    float sum = 0.0f;
#pragma unroll
    for (int t = 0; t < 2; ++t)
#pragma unroll
      for (int r = 0; r < 16; ++r) {
        const float p = exp2f(sa[t][r] - mnew);
        sa[t][r] = p;
        sum += p;
      }
    sum += __shfl_xor(sum, 32);
    lreg = lreg * alpha + sum;
#pragma unroll
    for (int v = 0; v < 2; ++v)
#pragma unroll
      for (int r = 0; r < 16; ++r) oacc[v][r] *= alpha;

#pragma unroll
    for (int t = 0; t < 2; ++t)
#pragma unroll
      for (int g = 0; g < 4; ++g) {
        bf16x4 pv;
#pragma unroll
        for (int i = 0; i < 4; ++i) pv[i] = (__bf16)sa[t][4 * g + i];
        const int kc = 4 * t + g;
        *(bf16x4*)&Pb[l32 * 64 + ((kc ^ (l32 & 7)) * 8) + 4 * half] = pv;
      }

    bf16x8 pf[4];
#pragma unroll
    for (int c = 0; c < 4; ++c)
      pf[c] = *(const bf16x8*)&Pb[l32 * 64 + (((2 * c + half) ^ (l32 & 7)) * 8)];
#pragma unroll
    for (int v = 0; v < 2; ++v)
#pragma unroll
      for (int c = 0; c < 4; ++c)
        oacc[v] = __builtin_amdgcn_mfma_f32_32x32x16_bf16(vf[v][c], pf[c], oacc[v], 0, 0, 0);
  }

  const float linv = 1.0f / lreg;
#pragma unroll
  for (int v = 0; v < 2; ++v)
#pragma unroll
    for (int g = 0; g < 4; ++g) {
      bf16x4 ov;
#pragma unroll
      for (int i = 0; i < 4; ++i) ov[i] = (__bf16)(oacc[v][4 * g + i] * linv);
      const int dc = 4 * v + g;
      *(bf16x4*)&Pb[l32 * 64 + ((dc ^ (l32 & 7)) * 8) + 4 * half] = ov;
    }
#pragma unroll
  for (int cc = 0; cc < 4; ++cc) {
    const int c = cc * 64 + lane;
    const int r = c >> 3, g = c & 7;
    const bf16x8 od = *(const bf16x8*)&Pb[r * 64 + ((g ^ (r & 7)) * 8)];
    const int srow = qt * BQ + w * 32 + r;
    *(bf16x8*)&attn_o[((size_t)b * S + srow) * 1024 + h * 64 + g * 8] = od;
  }
}

// ---------------- launch ----------------
extern "C" void kernel_launch(void* const* d_in, const int* in_sizes, int n_in,
                              void* d_out, int out_size, void* d_ws, size_t ws_size,
                              hipStream_t stream) {
  const float* inputs = (const float*)d_in[0];
  const float* ln1_g  = (const float*)d_in[1];
  const float* ln1_b  = (const float*)d_in[2];
  const float* Wq     = (const float*)d_in[3];
  const float* Wk     = (const float*)d_in[4];
  const float* Wv     = (const float*)d_in[5];
  const float* Wo     = (const float*)d_in[6];
  const float* ln2_g  = (const float*)d_in[7];
  const float* ln2_b  = (const float*)d_in[8];
  const float* Wfc2   = (const float*)d_in[9];
  const float* bfc2   = (const float*)d_in[10];
  const float* Wfc3   = (const float*)d_in[11];
  const float* bfc3   = (const float*)d_in[12];
  float* out = (float*)d_out;
  char* ws = (char*)d_ws;
  const size_t MB = 1024 * 1024;

  __bf16* Wqkv_t = (__bf16*)(ws);            // 6 MB: [3072][1024]
  __bf16* Wo_t   = (__bf16*)(ws + 6 * MB);   // 2 MB
  __bf16* Wfc2_t = (__bf16*)(ws + 8 * MB);   // 8 MB: [4096][1024]
  __bf16* Wfc3_t = (__bf16*)(ws + 16 * MB);  // 8 MB: [1024][4096]
  __bf16* xb     = (__bf16*)(ws + 24 * MB);  // 8 MB; reused as attn_o
  __bf16* attn_o = xb;
  __bf16* qkv    = (__bf16*)(ws + 32 * MB);  // 24 MB; reused:
  float*  mlp_in = (float*)(ws + 32 * MB);   //   16 MB
  __bf16* h2     = (__bf16*)(ws + 48 * MB);  //   8 MB
  __bf16* qrb    = (__bf16*)(ws + 56 * MB);  // 8 MB; qr/kr/vt reused as hbuf
  __bf16* krb    = (__bf16*)(ws + 64 * MB);
  __bf16* vtb    = (__bf16*)(ws + 72 * MB);
  __bf16* hbuf   = (__bf16*)(ws + 56 * MB);  // 32 MB (after attention)

  const dim3 tb(32, 8);
  transpose_cast_qkv<<<dim3(32, 32, 3), tb, 0, stream>>>(Wq, Wk, Wv, Wqkv_t);
  transpose_cast<<<dim3(32, 32),  tb, 0, stream>>>(Wo,   Wo_t,   1024, 1024);
  transpose_cast<<<dim3(128, 32), tb, 0, stream>>>(Wfc2, Wfc2_t, 1024, 4096);
  transpose_cast<<<dim3(32, 128), tb, 0, stream>>>(Wfc3, Wfc3_t, 4096, 1024);

  ln_kernel<<<4096, 256, 0, stream>>>(inputs, ln1_g, ln1_b, xb);

  gemm_bf16<64, EPI_BF16><<<dim3(24, 64), 256, 0, stream>>>(
      xb, Wqkv_t, qkv, nullptr, nullptr, nullptr, 4096, 3072, 1024);

  rope_qk<<<8192, 256, 0, stream>>>(qkv, qrb, krb);
  v_transpose<<<dim3(32, 16, 2), 256, 0, stream>>>(qkv, vtb);

  attn_kernel<<<dim3(16, 16, 2), 256, 0, stream>>>(qrb, krb, vtb, attn_o);

  gemm_bf16<64, EPI_RES_F32><<<dim3(8, 64), 256, 0, stream>>>(
      attn_o, Wo_t, nullptr, mlp_in, nullptr, inputs, 4096, 1024, 1024);

  ln_kernel<<<4096, 256, 0, stream>>>(mlp_in, ln2_g, ln2_b, h2);

  gemm_bf16<128, EPI_GELU_BF16><<<dim3(32, 32), 256, 0, stream>>>(
      h2, Wfc2_t, hbuf, nullptr, bfc2, nullptr, 4096, 4096, 1024);

  gemm_bf16<64, EPI_BIAS_RES_F32><<<dim3(8, 64), 256, 0, stream>>>(
      hbuf, Wfc3_t, nullptr, out, bfc3, mlp_in, 4096, 1024, 4096);
}

// Round 9
// 387.023 us; speedup vs baseline: 1.0433x; 1.0433x over previous
//
#include <hip/hip_runtime.h>
#include <cstdint>
#include <cstddef>

// ---------------- common types / helpers ----------------
typedef __bf16 bf16x8 __attribute__((ext_vector_type(8)));
typedef __bf16 bf16x4 __attribute__((ext_vector_type(4)));
typedef float  f32x4  __attribute__((ext_vector_type(4)));
typedef float  f32x16 __attribute__((ext_vector_type(16)));

__device__ __forceinline__ void load16_to_lds(const void* g, void* l) {
  __builtin_amdgcn_global_load_lds(
      (const __attribute__((address_space(1))) void*)g,
      (__attribute__((address_space(3))) void*)l, 16, 0, 0);
}

// ---------------- weight cast+transpose: f32 (K,N) -> bf16 (N,K) ----------------
__global__ __launch_bounds__(256) void transpose_cast(
    const float* __restrict__ src, __bf16* __restrict__ dst, int K, int N)
{
  __shared__ float tile[32][33];
  const int n0 = blockIdx.x * 32, k0 = blockIdx.y * 32;
  const int tx = threadIdx.x, ty = threadIdx.y; // (32,8)
#pragma unroll
  for (int i = 0; i < 32; i += 8)
    tile[ty + i][tx] = src[(size_t)(k0 + ty + i) * N + n0 + tx];
  __syncthreads();
#pragma unroll
  for (int i = 0; i < 32; i += 8)
    dst[(size_t)(n0 + ty + i) * K + k0 + tx] = (__bf16)tile[tx][ty + i];
}

// 3x 1024x1024 in one launch (z picks the weight)
__global__ __launch_bounds__(256) void transpose_cast_qkv(
    const float* __restrict__ s0, const float* __restrict__ s1,
    const float* __restrict__ s2, __bf16* __restrict__ dst)
{
  __shared__ float tile[32][33];
  const float* src = blockIdx.z == 0 ? s0 : blockIdx.z == 1 ? s1 : s2;
  __bf16* d = dst + (size_t)blockIdx.z * 1024 * 1024;
  const int n0 = blockIdx.x * 32, k0 = blockIdx.y * 32;
  const int tx = threadIdx.x, ty = threadIdx.y; // (32,8)
#pragma unroll
  for (int i = 0; i < 32; i += 8)
    tile[ty + i][tx] = src[(size_t)(k0 + ty + i) * 1024 + n0 + tx];
  __syncthreads();
#pragma unroll
  for (int i = 0; i < 32; i += 8)
    d[(size_t)(n0 + ty + i) * 1024 + k0 + tx] = (__bf16)tile[tx][ty + i];
}

// ---------------- LayerNorm: f32 row(1024) -> bf16 ----------------
__global__ __launch_bounds__(256) void ln_kernel(
    const float* __restrict__ x, const float* __restrict__ g,
    const float* __restrict__ bta, __bf16* __restrict__ out)
{
  const int row = blockIdx.x;
  const int t = threadIdx.x;
  const float4 v = ((const float4*)(x + (size_t)row * 1024))[t];
  float s  = v.x + v.y + v.z + v.w;
  float ss = v.x * v.x + v.y * v.y + v.z * v.z + v.w * v.w;
#pragma unroll
  for (int o = 32; o > 0; o >>= 1) { s += __shfl_down(s, o); ss += __shfl_down(ss, o); }
  __shared__ float rs[4], rss[4];
  const int w = t >> 6, l = t & 63;
  if (l == 0) { rs[w] = s; rss[w] = ss; }
  __syncthreads();
  s  = rs[0] + rs[1] + rs[2] + rs[3];
  ss = rss[0] + rss[1] + rss[2] + rss[3];
  const float mu = s * (1.0f / 1024.0f);
  const float var = ss * (1.0f / 1024.0f) - mu * mu;
  const float rstd = rsqrtf(var + 1e-5f);
  const float4 gg = ((const float4*)g)[t];
  const float4 bb = ((const float4*)bta)[t];
  __bf16* o = out + (size_t)row * 1024 + t * 4;
  o[0] = (__bf16)((v.x - mu) * rstd * gg.x + bb.x);
  o[1] = (__bf16)((v.y - mu) * rstd * gg.y + bb.y);
  o[2] = (__bf16)((v.z - mu) * rstd * gg.z + bb.z);
  o[3] = (__bf16)((v.w - mu) * rstd * gg.w + bb.w);
}

// ---------------- bf16 MFMA GEMM: C = A(MxK) * Bt(NxK)^T ----------------
// Double-buffered, ONE barrier per staged tile. ORDER MATTERS (round-8
// lesson): frag ds_reads FIRST, prefetch AFTER -- a vmem op before the
// ds_reads makes the compiler insert s_waitcnt vmcnt(0) before them (it
// can't prove the in-flight global_load_lds doesn't alias buffer p),
// serializing every iteration on full load latency (404 vs 383 us).
// KB=64 (Wo/FC3): two k-substeps per staged tile -> half the barriers;
// 128B rows need the XOR chunk swizzle (cb^(r&7)) to stay bank-clean.
enum { EPI_BF16 = 0, EPI_RES_F32 = 1, EPI_GELU_BF16 = 2, EPI_BIAS_RES_F32 = 3 };

template <int TM, int KB, int EPI>
__global__ __launch_bounds__(256, 2) void gemm_bf16(
    const __bf16* __restrict__ A, const __bf16* __restrict__ Bt,
    __bf16* __restrict__ outb, float* __restrict__ outf,
    const float* __restrict__ bias, const float* __restrict__ res,
    int M, int N, int K)
{
  constexpr int MT = TM / 32;           // mt tiles per wave
  constexpr int KS = KB / 32;           // k-substeps per staged tile
  __shared__ __bf16 As[2][TM * KB];
  __shared__ __bf16 Bs[2][128 * KB];
  const int tid  = threadIdx.x;
  const int lane = tid & 63, w = tid >> 6;
  const int wm = w >> 1, wn = w & 1;
  const int quad = lane >> 4, l16 = lane & 15;
  const int m0 = blockIdx.y * TM, n0 = blockIdx.x * 128;

  f32x4 acc[MT][4] = {};
  const __bf16* Ag = A  + (size_t)m0 * K;
  const __bf16* Bg = Bt + (size_t)n0 * K;

  // staging helper indices: chunk c -> row r = c/(KB/8), chunk-in-row cb
  auto stageA = [&](int buf, int k0) {
#pragma unroll
    for (int r2 = 0; r2 < TM * KB / 8 / 256; ++r2) {
      const int c = r2 * 256 + tid;
      const int r = c / (KB / 8), cb = c % (KB / 8);
      const int g = (KB == 64) ? (cb ^ (r & 7)) : cb;   // swizzle for 128B rows
      load16_to_lds(Ag + (size_t)r * K + k0 + g * 8, &As[buf][c * 8]);
    }
  };
  auto stageB = [&](int buf, int k0) {
#pragma unroll
    for (int r2 = 0; r2 < 128 * KB / 8 / 256; ++r2) {
      const int c = r2 * 256 + tid;
      const int r = c / (KB / 8), cb = c % (KB / 8);
      const int g = (KB == 64) ? (cb ^ (r & 7)) : cb;
      load16_to_lds(Bg + (size_t)r * K + k0 + g * 8, &Bs[buf][c * 8]);
    }
  };

  stageA(0, 0);
  stageB(0, 0);

  const int nk = K / KB;
  for (int kt = 0; kt < nk; ++kt) {
    __syncthreads();               // drains prefetch for tile kt
    const int p = kt & 1;

    // fragment ds_reads FIRST (no vmem op may precede them -- see header)
    bf16x8 af[MT][KS], bfr[4][KS];
#pragma unroll
    for (int mt = 0; mt < MT; ++mt) {
      const int row = wm * (TM / 2) + mt * 16 + l16;
#pragma unroll
      for (int ks = 0; ks < KS; ++ks) {
        const int ch = (KB == 64) ? ((ks * 4 + quad) ^ (row & 7)) : quad;
        af[mt][ks] = *(const bf16x8*)&As[p][row * KB + ch * 8];
      }
    }
#pragma unroll
    for (int nt = 0; nt < 4; ++nt) {
      const int row = wn * 64 + nt * 16 + l16;
#pragma unroll
      for (int ks = 0; ks < KS; ++ks) {
        const int ch = (KB == 64) ? ((ks * 4 + quad) ^ (row & 7)) : quad;
        bfr[nt][ks] = *(const bf16x8*)&Bs[p][row * KB + ch * 8];
      }
    }

    if (kt + 1 < nk) {             // prefetch AFTER the frag reads
      stageA(1 - p, (kt + 1) * KB);
      stageB(1 - p, (kt + 1) * KB);
    }

#pragma unroll
    for (int ks = 0; ks < KS; ++ks)
#pragma unroll
      for (int mt = 0; mt < MT; ++mt)
#pragma unroll
        for (int nt = 0; nt < 4; ++nt)
          acc[mt][nt] = __builtin_amdgcn_mfma_f32_16x16x32_bf16(
              af[mt][ks], bfr[nt][ks], acc[mt][nt], 0, 0, 0);
  }

#pragma unroll
  for (int mt = 0; mt < MT; ++mt) {
#pragma unroll
    for (int nt = 0; nt < 4; ++nt) {
      const int col = n0 + wn * 64 + nt * 16 + l16;
#pragma unroll
      for (int i = 0; i < 4; ++i) {
        const int row = m0 + wm * (TM / 2) + mt * 16 + quad * 4 + i;
        float v = acc[mt][nt][i];
        const size_t idx = (size_t)row * N + col;
        if (EPI == EPI_BF16) {
          outb[idx] = (__bf16)v;
        } else if (EPI == EPI_RES_F32) {
          outf[idx] = v + res[idx];
        } else if (EPI == EPI_GELU_BF16) {
          v += bias[col];
          outb[idx] = (__bf16)(0.5f * v * (1.0f + erff(v * 0.70710678118f)));
        } else {
          v += bias[col];
          outf[idx] = v + res[idx];
        }
      }
    }
  }
}

// ---------------- RoPE for q,k: qkv(4096x3072) -> qr,kr [b][h][s][d] --------
// Q is pre-scaled by 0.125*log2(e) so attention scores come out in the exp2
// domain: softmax then needs only sub+v_exp per element.
__global__ __launch_bounds__(256) void rope_qk(
    const __bf16* __restrict__ qkv, __bf16* __restrict__ qr, __bf16* __restrict__ kr)
{
  const int idx = blockIdx.x * 256 + threadIdx.x; // (b,s,h,d2)
  const int d2 = idx & 31;
  const int h  = (idx >> 5) & 15;
  const int bs = idx >> 9;       // b*2048+s
  const int s  = bs & 2047;
  const int b  = bs >> 11;
  const float inv_freq = exp2f(-((float)d2 * (1.0f / 32.0f)) * 13.2877123795f); // log2(1e4)
  const float ang = (float)s * inv_freq;
  const float c = cosf(ang), sn = sinf(ang);
  const float QS = 0.125f * 1.44269504f;  // (1/sqrt(64)) * log2(e)
  const __bf16* qp = qkv + (size_t)bs * 3072 + h * 64 + 2 * d2;
  const __bf16* kp = qp + 1024;
  const float q0 = (float)qp[0], q1 = (float)qp[1];
  const float k0 = (float)kp[0], k1 = (float)kp[1];
  const size_t o = ((size_t)(b * 16 + h) * 2048 + s) * 64 + 2 * d2;
  qr[o]     = (__bf16)((q0 * c - q1 * sn) * QS);
  qr[o + 1] = (__bf16)((q1 * c + q0 * sn) * QS);
  kr[o]     = (__bf16)(k0 * c - k1 * sn);
  kr[o + 1] = (__bf16)(k1 * c + k0 * sn);
}

// ---------------- V transpose: qkv v-cols -> vt [b][h][d][s] ----------------
__global__ __launch_bounds__(256) void v_transpose(
    const __bf16* __restrict__ qkv, __bf16* __restrict__ vt)
{
  __shared__ __bf16 t[64][72];
  const int st = blockIdx.x, h = blockIdx.y, b = blockIdx.z;
  const int tx = threadIdx.x & 63, ty = threadIdx.x >> 6; // 64x4
  const int s0 = st * 64;
  const __bf16* src = qkv + ((size_t)(b * 2048 + s0)) * 3072 + 2048 + h * 64;
#pragma unroll
  for (int i = 0; i < 64; i += 4)
    t[ty + i][tx] = src[(size_t)(ty + i) * 3072 + tx];
  __syncthreads();
  __bf16* dst = vt + ((size_t)(b * 16 + h) * 64) * 2048 + s0;
#pragma unroll
  for (int i = 0; i < 64; i += 4)
    dst[(size_t)(ty + i) * 2048 + tx] = t[tx][ty + i];
}

// ---------------- flash attention v5: 32x32x16, S^T, exp2 softmax -----------
// r7 ordering restored (frag reads BEFORE prefetch -- see GEMM header);
// exp2-domain softmax kept (Q pre-scaled in rope_qk).
__global__ __launch_bounds__(256, 2) void attn_kernel(
    const __bf16* __restrict__ qr, const __bf16* __restrict__ kr,
    const __bf16* __restrict__ vt, __bf16* __restrict__ attn_o)
{
  constexpr int S = 2048, DH = 64, NH = 16, BQ = 128, BKK = 64;
  __shared__ __align__(16) __bf16 smem[24576];  // 48 KB
  __bf16* Qs   = smem;                       // [128][64] swizzled; -> per-wave Pb
  __bf16* Ksb  = smem + 8192;                // 2 x [64][64] swizzled
  __bf16* Vtsb = smem + 16384;               // 2 x [64][64] swizzled

  const int tid = threadIdx.x;
  const int lane = tid & 63, w = tid >> 6;
  const int l32 = lane & 31, half = lane >> 5;
  const int qt = blockIdx.x, h = blockIdx.y, b = blockIdx.z;
  const int bh = b * NH + h;
  const __bf16* Q  = qr + ((size_t)bh * S + qt * BQ) * DH;
  const __bf16* Kp = kr + (size_t)bh * S * DH;
  const __bf16* Vp = vt + (size_t)bh * DH * S;
  __bf16* Pb = Qs + w * 2048;                // wave-local [32][64] swizzled

#pragma unroll
  for (int r4 = 0; r4 < 4; ++r4) {
    const int c = r4 * 256 + tid;
    const int r = c >> 3, cb = c & 7;
    load16_to_lds(Q + (size_t)r * DH + ((cb ^ (r & 7)) * 8), &Qs[c * 8]);
  }
#pragma unroll
  for (int r2 = 0; r2 < 2; ++r2) {
    const int c = r2 * 256 + tid;
    const int r = c >> 3, cb = c & 7;
    const int cg = (cb ^ (r & 7)) * 8;
    load16_to_lds(Kp + (size_t)r * DH + cg, &Ksb[c * 8]);
    load16_to_lds(Vp + (size_t)r * S + cg, &Vtsb[c * 8]);
  }
  __syncthreads();

  bf16x8 qfB[4];
  {
    const int row = w * 32 + l32;
#pragma unroll
    for (int c = 0; c < 4; ++c)
      qfB[c] = *(const bf16x8*)&Qs[row * 64 + (((2 * c + half) ^ (row & 7)) * 8)];
  }

  float mreg = -3.0e38f, lreg = 0.0f;
  f32x16 oacc[2] = {};

  for (int kt = 0; kt < S / BKK; ++kt) {
    if (kt) __syncthreads();
    const __bf16* Ks  = Ksb  + (kt & 1) * 4096;
    const __bf16* Vts = Vtsb + (kt & 1) * 4096;

    // fragment reads first (no vmem op may precede them)
    bf16x8 kf[2][4], vf[2][4];
#pragma unroll
    for (int t = 0; t < 2; ++t) {
      const int row = 32 * t + l32;
#pragma unroll
      for (int c = 0; c < 4; ++c)
        kf[t][c] = *(const bf16x8*)&Ks[row * 64 + (((2 * c + half) ^ (l32 & 7)) * 8)];
    }
#pragma unroll
    for (int v = 0; v < 2; ++v) {
      const int row = 32 * v + l32;
#pragma unroll
      for (int c = 0; c < 4; ++c)
        vf[v][c] = *(const bf16x8*)&Vts[row * 64 + (((2 * c + half) ^ (l32 & 7)) * 8)];
    }

    // prefetch next K/V tile (after the frag reads)
    if (kt + 1 < S / BKK) {
      __bf16* Kn = Ksb  + ((kt + 1) & 1) * 4096;
      __bf16* Vn = Vtsb + ((kt + 1) & 1) * 4096;
      const size_t kk1 = (size_t)(kt + 1) * BKK;
#pragma unroll
      for (int r2 = 0; r2 < 2; ++r2) {
        const int c = r2 * 256 + tid;
        const int r = c >> 3, cb = c & 7;
        const int cg = (cb ^ (r & 7)) * 8;
        load16_to_lds(Kp + (kk1 + r) * DH + cg, &Kn[c * 8]);
        load16_to_lds(Vp + (size_t)r * S + kk1 + cg, &Vn[c * 8]);
      }
    }

    // S'^T = K (Q*log2e/8)^T  -- scores already in exp2 domain
    f32x16 sa[2] = {};
#pragma unroll
    for (int t = 0; t < 2; ++t)
#pragma unroll
      for (int c = 0; c < 4; ++c)
        sa[t] = __builtin_amdgcn_mfma_f32_32x32x16_bf16(kf[t][c], qfB[c], sa[t], 0, 0, 0);

    float mx = -3.0e38f;
#pragma unroll
    for (int t = 0; t < 2; ++t)
#pragma unroll
      for (int r = 0; r < 16; ++r) mx = fmaxf(mx, sa[t][r]);
    mx = fmaxf(mx, __shfl_xor(mx, 32));
    const float mnew = fmaxf(mreg, mx);
    const float alpha = exp2f(mreg - mnew);
    mreg = mnew;
    float sum = 0.0f;
#pragma unroll
    for (int t = 0; t < 2; ++t)
#pragma unroll
      for (int r = 0; r < 16; ++r) {
        const float p = exp2f(sa[t][r] - mnew);
        sa[t][r] = p;
        sum += p;
      }
    sum += __shfl_xor(sum, 32);
    lreg = lreg * alpha + sum;
#pragma unroll
    for (int v = 0; v < 2; ++v)
#pragma unroll
      for (int r = 0; r < 16; ++r) oacc[v][r] *= alpha;

#pragma unroll
    for (int t = 0; t < 2; ++t)
#pragma unroll
      for (int g = 0; g < 4; ++g) {
        bf16x4 pv;
#pragma unroll
        for (int i = 0; i < 4; ++i) pv[i] = (__bf16)sa[t][4 * g + i];
        const int kc = 4 * t + g;
        *(bf16x4*)&Pb[l32 * 64 + ((kc ^ (l32 & 7)) * 8) + 4 * half] = pv;
      }

    bf16x8 pf[4];
#pragma unroll
    for (int c = 0; c < 4; ++c)
      pf[c] = *(const bf16x8*)&Pb[l32 * 64 + (((2 * c + half) ^ (l32 & 7)) * 8)];
#pragma unroll
    for (int v = 0; v < 2; ++v)
#pragma unroll
      for (int c = 0; c < 4; ++c)
        oacc[v] = __builtin_amdgcn_mfma_f32_32x32x16_bf16(vf[v][c], pf[c], oacc[v], 0, 0, 0);
  }

  const float linv = 1.0f / lreg;
#pragma unroll
  for (int v = 0; v < 2; ++v)
#pragma unroll
    for (int g = 0; g < 4; ++g) {
      bf16x4 ov;
#pragma unroll
      for (int i = 0; i < 4; ++i) ov[i] = (__bf16)(oacc[v][4 * g + i] * linv);
      const int dc = 4 * v + g;
      *(bf16x4*)&Pb[l32 * 64 + ((dc ^ (l32 & 7)) * 8) + 4 * half] = ov;
    }
#pragma unroll
  for (int cc = 0; cc < 4; ++cc) {
    const int c = cc * 64 + lane;
    const int r = c >> 3, g = c & 7;
    const bf16x8 od = *(const bf16x8*)&Pb[r * 64 + ((g ^ (r & 7)) * 8)];
    const int srow = qt * BQ + w * 32 + r;
    *(bf16x8*)&attn_o[((size_t)b * S + srow) * 1024 + h * 64 + g * 8] = od;
  }
}

// ---------------- launch ----------------
extern "C" void kernel_launch(void* const* d_in, const int* in_sizes, int n_in,
                              void* d_out, int out_size, void* d_ws, size_t ws_size,
                              hipStream_t stream) {
  const float* inputs = (const float*)d_in[0];
  const float* ln1_g  = (const float*)d_in[1];
  const float* ln1_b  = (const float*)d_in[2];
  const float* Wq     = (const float*)d_in[3];
  const float* Wk     = (const float*)d_in[4];
  const float* Wv     = (const float*)d_in[5];
  const float* Wo     = (const float*)d_in[6];
  const float* ln2_g  = (const float*)d_in[7];
  const float* ln2_b  = (const float*)d_in[8];
  const float* Wfc2   = (const float*)d_in[9];
  const float* bfc2   = (const float*)d_in[10];
  const float* Wfc3   = (const float*)d_in[11];
  const float* bfc3   = (const float*)d_in[12];
  float* out = (float*)d_out;
  char* ws = (char*)d_ws;
  const size_t MB = 1024 * 1024;

  __bf16* Wqkv_t = (__bf16*)(ws);            // 6 MB: [3072][1024]
  __bf16* Wo_t   = (__bf16*)(ws + 6 * MB);   // 2 MB
  __bf16* Wfc2_t = (__bf16*)(ws + 8 * MB);   // 8 MB: [4096][1024]
  __bf16* Wfc3_t = (__bf16*)(ws + 16 * MB);  // 8 MB: [1024][4096]
  __bf16* xb     = (__bf16*)(ws + 24 * MB);  // 8 MB; reused as attn_o
  __bf16* attn_o = xb;
  __bf16* qkv    = (__bf16*)(ws + 32 * MB);  // 24 MB; reused:
  float*  mlp_in = (float*)(ws + 32 * MB);   //   16 MB
  __bf16* h2     = (__bf16*)(ws + 48 * MB);  //   8 MB
  __bf16* qrb    = (__bf16*)(ws + 56 * MB);  // 8 MB; qr/kr/vt reused as hbuf
  __bf16* krb    = (__bf16*)(ws + 64 * MB);
  __bf16* vtb    = (__bf16*)(ws + 72 * MB);
  __bf16* hbuf   = (__bf16*)(ws + 56 * MB);  // 32 MB (after attention)

  const dim3 tb(32, 8);
  transpose_cast_qkv<<<dim3(32, 32, 3), tb, 0, stream>>>(Wq, Wk, Wv, Wqkv_t);
  transpose_cast<<<dim3(32, 32),  tb, 0, stream>>>(Wo,   Wo_t,   1024, 1024);
  transpose_cast<<<dim3(128, 32), tb, 0, stream>>>(Wfc2, Wfc2_t, 1024, 4096);
  transpose_cast<<<dim3(32, 128), tb, 0, stream>>>(Wfc3, Wfc3_t, 4096, 1024);

  ln_kernel<<<4096, 256, 0, stream>>>(inputs, ln1_g, ln1_b, xb);

  gemm_bf16<64, 32, EPI_BF16><<<dim3(24, 64), 256, 0, stream>>>(
      xb, Wqkv_t, qkv, nullptr, nullptr, nullptr, 4096, 3072, 1024);

  rope_qk<<<8192, 256, 0, stream>>>(qkv, qrb, krb);
  v_transpose<<<dim3(32, 16, 2), 256, 0, stream>>>(qkv, vtb);

  attn_kernel<<<dim3(16, 16, 2), 256, 0, stream>>>(qrb, krb, vtb, attn_o);

  gemm_bf16<64, 64, EPI_RES_F32><<<dim3(8, 64), 256, 0, stream>>>(
      attn_o, Wo_t, nullptr, mlp_in, nullptr, inputs, 4096, 1024, 1024);

  ln_kernel<<<4096, 256, 0, stream>>>(mlp_in, ln2_g, ln2_b, h2);

  gemm_bf16<128, 32, EPI_GELU_BF16><<<dim3(32, 32), 256, 0, stream>>>(
      h2, Wfc2_t, hbuf, nullptr, bfc2, nullptr, 4096, 4096, 1024);

  gemm_bf16<64, 64, EPI_BIAS_RES_F32><<<dim3(8, 64), 256, 0, stream>>>(
      hbuf, Wfc3_t, nullptr, out, bfc3, mlp_in, 4096, 1024, 4096);
}

// Round 10
// 350.239 us; speedup vs baseline: 1.1528x; 1.1050x over previous
//
#include <hip/hip_runtime.h>
#include <cstdint>
#include <cstddef>

// ---------------- common types / helpers ----------------
typedef __bf16 bf16x8 __attribute__((ext_vector_type(8)));
typedef __bf16 bf16x4 __attribute__((ext_vector_type(4)));
typedef float  f32x4  __attribute__((ext_vector_type(4)));
typedef float  f32x16 __attribute__((ext_vector_type(16)));

__device__ __forceinline__ void load16_to_lds(const void* g, void* l) {
  __builtin_amdgcn_global_load_lds(
      (const __attribute__((address_space(1))) void*)g,
      (__attribute__((address_space(3))) void*)l, 16, 0, 0);
}

// ---------------- weight cast+transpose: f32 (K,N) -> bf16 (N,K) ----------------
__global__ __launch_bounds__(256) void transpose_cast(
    const float* __restrict__ src, __bf16* __restrict__ dst, int K, int N)
{
  __shared__ float tile[32][33];
  const int n0 = blockIdx.x * 32, k0 = blockIdx.y * 32;
  const int tx = threadIdx.x, ty = threadIdx.y; // (32,8)
#pragma unroll
  for (int i = 0; i < 32; i += 8)
    tile[ty + i][tx] = src[(size_t)(k0 + ty + i) * N + n0 + tx];
  __syncthreads();
#pragma unroll
  for (int i = 0; i < 32; i += 8)
    dst[(size_t)(n0 + ty + i) * K + k0 + tx] = (__bf16)tile[tx][ty + i];
}

// 3x 1024x1024 in one launch (z picks the weight)
__global__ __launch_bounds__(256) void transpose_cast_qkv(
    const float* __restrict__ s0, const float* __restrict__ s1,
    const float* __restrict__ s2, __bf16* __restrict__ dst)
{
  __shared__ float tile[32][33];
  const float* src = blockIdx.z == 0 ? s0 : blockIdx.z == 1 ? s1 : s2;
  __bf16* d = dst + (size_t)blockIdx.z * 1024 * 1024;
  const int n0 = blockIdx.x * 32, k0 = blockIdx.y * 32;
  const int tx = threadIdx.x, ty = threadIdx.y; // (32,8)
#pragma unroll
  for (int i = 0; i < 32; i += 8)
    tile[ty + i][tx] = src[(size_t)(k0 + ty + i) * 1024 + n0 + tx];
  __syncthreads();
#pragma unroll
  for (int i = 0; i < 32; i += 8)
    d[(size_t)(n0 + ty + i) * 1024 + k0 + tx] = (__bf16)tile[tx][ty + i];
}

// ---------------- LayerNorm: f32 row(1024) -> bf16 ----------------
__global__ __launch_bounds__(256) void ln_kernel(
    const float* __restrict__ x, const float* __restrict__ g,
    const float* __restrict__ bta, __bf16* __restrict__ out)
{
  const int row = blockIdx.x;
  const int t = threadIdx.x;
  const float4 v = ((const float4*)(x + (size_t)row * 1024))[t];
  float s  = v.x + v.y + v.z + v.w;
  float ss = v.x * v.x + v.y * v.y + v.z * v.z + v.w * v.w;
#pragma unroll
  for (int o = 32; o > 0; o >>= 1) { s += __shfl_down(s, o); ss += __shfl_down(ss, o); }
  __shared__ float rs[4], rss[4];
  const int w = t >> 6, l = t & 63;
  if (l == 0) { rs[w] = s; rss[w] = ss; }
  __syncthreads();
  s  = rs[0] + rs[1] + rs[2] + rs[3];
  ss = rss[0] + rss[1] + rss[2] + rss[3];
  const float mu = s * (1.0f / 1024.0f);
  const float var = ss * (1.0f / 1024.0f) - mu * mu;
  const float rstd = rsqrtf(var + 1e-5f);
  const float4 gg = ((const float4*)g)[t];
  const float4 bb = ((const float4*)bta)[t];
  __bf16* o = out + (size_t)row * 1024 + t * 4;
  o[0] = (__bf16)((v.x - mu) * rstd * gg.x + bb.x);
  o[1] = (__bf16)((v.y - mu) * rstd * gg.y + bb.y);
  o[2] = (__bf16)((v.z - mu) * rstd * gg.z + bb.z);
  o[3] = (__bf16)((v.w - mu) * rstd * gg.w + bb.w);
}

// ---------------- bf16 MFMA GEMM: C = A(MxK) * Bt(NxK)^T ----------------
// Double-buffered, ONE barrier per staged tile. Frag ds_reads FIRST,
// prefetch AFTER (round-8: a vmem op before the ds_reads forces a
// vmcnt(0) wait before them -- compiler can't prove non-aliasing).
// KB=64 (Wo/FC3): half the barriers; XOR chunk swizzle for 128B rows.
// TM=128 for QKV/FC2 (grids >= 768: occupancy fine, 2x arithmetic
// intensity per staged byte vs TM=64).
enum { EPI_BF16 = 0, EPI_RES_F32 = 1, EPI_GELU_BF16 = 2, EPI_BIAS_RES_F32 = 3 };

template <int TM, int KB, int EPI>
__global__ __launch_bounds__(256, 2) void gemm_bf16(
    const __bf16* __restrict__ A, const __bf16* __restrict__ Bt,
    __bf16* __restrict__ outb, float* __restrict__ outf,
    const float* __restrict__ bias, const float* __restrict__ res,
    int M, int N, int K)
{
  constexpr int MT = TM / 32;           // mt tiles per wave
  constexpr int KS = KB / 32;           // k-substeps per staged tile
  __shared__ __bf16 As[2][TM * KB];
  __shared__ __bf16 Bs[2][128 * KB];
  const int tid  = threadIdx.x;
  const int lane = tid & 63, w = tid >> 6;
  const int wm = w >> 1, wn = w & 1;
  const int quad = lane >> 4, l16 = lane & 15;
  const int m0 = blockIdx.y * TM, n0 = blockIdx.x * 128;

  f32x4 acc[MT][4] = {};
  const __bf16* Ag = A  + (size_t)m0 * K;
  const __bf16* Bg = Bt + (size_t)n0 * K;

  auto stageA = [&](int buf, int k0) {
#pragma unroll
    for (int r2 = 0; r2 < TM * KB / 8 / 256; ++r2) {
      const int c = r2 * 256 + tid;
      const int r = c / (KB / 8), cb = c % (KB / 8);
      const int g = (KB == 64) ? (cb ^ (r & 7)) : cb;   // swizzle for 128B rows
      load16_to_lds(Ag + (size_t)r * K + k0 + g * 8, &As[buf][c * 8]);
    }
  };
  auto stageB = [&](int buf, int k0) {
#pragma unroll
    for (int r2 = 0; r2 < 128 * KB / 8 / 256; ++r2) {
      const int c = r2 * 256 + tid;
      const int r = c / (KB / 8), cb = c % (KB / 8);
      const int g = (KB == 64) ? (cb ^ (r & 7)) : cb;
      load16_to_lds(Bg + (size_t)r * K + k0 + g * 8, &Bs[buf][c * 8]);
    }
  };

  stageA(0, 0);
  stageB(0, 0);

  const int nk = K / KB;
  for (int kt = 0; kt < nk; ++kt) {
    __syncthreads();               // drains prefetch for tile kt
    const int p = kt & 1;

    // fragment ds_reads FIRST (no vmem op may precede them)
    bf16x8 af[MT][KS], bfr[4][KS];
#pragma unroll
    for (int mt = 0; mt < MT; ++mt) {
      const int row = wm * (TM / 2) + mt * 16 + l16;
#pragma unroll
      for (int ks = 0; ks < KS; ++ks) {
        const int ch = (KB == 64) ? ((ks * 4 + quad) ^ (row & 7)) : quad;
        af[mt][ks] = *(const bf16x8*)&As[p][row * KB + ch * 8];
      }
    }
#pragma unroll
    for (int nt = 0; nt < 4; ++nt) {
      const int row = wn * 64 + nt * 16 + l16;
#pragma unroll
      for (int ks = 0; ks < KS; ++ks) {
        const int ch = (KB == 64) ? ((ks * 4 + quad) ^ (row & 7)) : quad;
        bfr[nt][ks] = *(const bf16x8*)&Bs[p][row * KB + ch * 8];
      }
    }

    if (kt + 1 < nk) {             // prefetch AFTER the frag reads
      stageA(1 - p, (kt + 1) * KB);
      stageB(1 - p, (kt + 1) * KB);
    }

#pragma unroll
    for (int ks = 0; ks < KS; ++ks)
#pragma unroll
      for (int mt = 0; mt < MT; ++mt)
#pragma unroll
        for (int nt = 0; nt < 4; ++nt)
          acc[mt][nt] = __builtin_amdgcn_mfma_f32_16x16x32_bf16(
              af[mt][ks], bfr[nt][ks], acc[mt][nt], 0, 0, 0);
  }

#pragma unroll
  for (int mt = 0; mt < MT; ++mt) {
#pragma unroll
    for (int nt = 0; nt < 4; ++nt) {
      const int col = n0 + wn * 64 + nt * 16 + l16;
#pragma unroll
      for (int i = 0; i < 4; ++i) {
        const int row = m0 + wm * (TM / 2) + mt * 16 + quad * 4 + i;
        float v = acc[mt][nt][i];
        const size_t idx = (size_t)row * N + col;
        if (EPI == EPI_BF16) {
          outb[idx] = (__bf16)v;
        } else if (EPI == EPI_RES_F32) {
          outf[idx] = v + res[idx];
        } else if (EPI == EPI_GELU_BF16) {
          v += bias[col];
          outb[idx] = (__bf16)(0.5f * v * (1.0f + erff(v * 0.70710678118f)));
        } else {
          v += bias[col];
          outf[idx] = v + res[idx];
        }
      }
    }
  }
}

// ---------------- RoPE for q,k: qkv(4096x3072) -> qr,kr [b][h][s][d] --------
// Q pre-scaled by 0.125*log2(e): scores land in the exp2 domain.
__global__ __launch_bounds__(256) void rope_qk(
    const __bf16* __restrict__ qkv, __bf16* __restrict__ qr, __bf16* __restrict__ kr)
{
  const int idx = blockIdx.x * 256 + threadIdx.x; // (b,s,h,d2)
  const int d2 = idx & 31;
  const int h  = (idx >> 5) & 15;
  const int bs = idx >> 9;       // b*2048+s
  const int s  = bs & 2047;
  const int b  = bs >> 11;
  const float inv_freq = exp2f(-((float)d2 * (1.0f / 32.0f)) * 13.2877123795f); // log2(1e4)
  const float ang = (float)s * inv_freq;
  const float c = cosf(ang), sn = sinf(ang);
  const float QS = 0.125f * 1.44269504f;  // (1/sqrt(64)) * log2(e)
  const __bf16* qp = qkv + (size_t)bs * 3072 + h * 64 + 2 * d2;
  const __bf16* kp = qp + 1024;
  const float q0 = (float)qp[0], q1 = (float)qp[1];
  const float k0 = (float)kp[0], k1 = (float)kp[1];
  const size_t o = ((size_t)(b * 16 + h) * 2048 + s) * 64 + 2 * d2;
  qr[o]     = (__bf16)((q0 * c - q1 * sn) * QS);
  qr[o + 1] = (__bf16)((q1 * c + q0 * sn) * QS);
  kr[o]     = (__bf16)(k0 * c - k1 * sn);
  kr[o + 1] = (__bf16)(k1 * c + k0 * sn);
}

// ---------------- V transpose: qkv v-cols -> vt [b][h][d][s] ----------------
__global__ __launch_bounds__(256) void v_transpose(
    const __bf16* __restrict__ qkv, __bf16* __restrict__ vt)
{
  __shared__ __bf16 t[64][72];
  const int st = blockIdx.x, h = blockIdx.y, b = blockIdx.z;
  const int tx = threadIdx.x & 63, ty = threadIdx.x >> 6; // 64x4
  const int s0 = st * 64;
  const __bf16* src = qkv + ((size_t)(b * 2048 + s0)) * 3072 + 2048 + h * 64;
#pragma unroll
  for (int i = 0; i < 64; i += 4)
    t[ty + i][tx] = src[(size_t)(ty + i) * 3072 + tx];
  __syncthreads();
  __bf16* dst = vt + ((size_t)(b * 16 + h) * 64) * 2048 + s0;
#pragma unroll
  for (int i = 0; i < 64; i += 4)
    dst[(size_t)(ty + i) * 2048 + tx] = t[tx][ty + i];
}

// ---------------- flash attention v6: 32x32x16, S^T, raw-v_exp softmax ------
// Round-9 lesson: exp2f lowers to __ocml_exp2_f32 (denormal fixup: ~6 extra
// VALU/call -> +10us). __builtin_amdgcn_exp2f is the bare v_exp_f32 (which IS
// exp2), handles -3e38 -> 0 natively. r7 ordering (frag reads before
// prefetch) kept.
__global__ __launch_bounds__(256, 2) void attn_kernel(
    const __bf16* __restrict__ qr, const __bf16* __restrict__ kr,
    const __bf16* __restrict__ vt, __bf16* __restrict__ attn_o)
{
  constexpr int S = 2048, DH = 64, NH = 16, BQ = 128, BKK = 64;
  __shared__ __align__(16) __bf16 smem[24576];  // 48 KB
  __bf16* Qs   = smem;                       // [128][64] swizzled; -> per-wave Pb
  __bf16* Ksb  = smem + 8192;                // 2 x [64][64] swizzled
  __bf16* Vtsb = smem + 16384;               // 2 x [64][64] swizzled

  const int tid = threadIdx.x;
  const int lane = tid & 63, w = tid >> 6;
  const int l32 = lane & 31, half = lane >> 5;
  const int qt = blockIdx.x, h = blockIdx.y, b = blockIdx.z;
  const int bh = b * NH + h;
  const __bf16* Q  = qr + ((size_t)bh * S + qt * BQ) * DH;
  const __bf16* Kp = kr + (size_t)bh * S * DH;
  const __bf16* Vp = vt + (size_t)bh * DH * S;
  __bf16* Pb = Qs + w * 2048;                // wave-local [32][64] swizzled

#pragma unroll
  for (int r4 = 0; r4 < 4; ++r4) {
    const int c = r4 * 256 + tid;
    const int r = c >> 3, cb = c & 7;
    load16_to_lds(Q + (size_t)r * DH + ((cb ^ (r & 7)) * 8), &Qs[c * 8]);
  }
#pragma unroll
  for (int r2 = 0; r2 < 2; ++r2) {
    const int c = r2 * 256 + tid;
    const int r = c >> 3, cb = c & 7;
    const int cg = (cb ^ (r & 7)) * 8;
    load16_to_lds(Kp + (size_t)r * DH + cg, &Ksb[c * 8]);
    load16_to_lds(Vp + (size_t)r * S + cg, &Vtsb[c * 8]);
  }
  __syncthreads();

  bf16x8 qfB[4];
  {
    const int row = w * 32 + l32;
#pragma unroll
    for (int c = 0; c < 4; ++c)
      qfB[c] = *(const bf16x8*)&Qs[row * 64 + (((2 * c + half) ^ (row & 7)) * 8)];
  }

  float mreg = -3.0e38f, lreg = 0.0f;
  f32x16 oacc[2] = {};

  for (int kt = 0; kt < S / BKK; ++kt) {
    if (kt) __syncthreads();
    const __bf16* Ks  = Ksb  + (kt & 1) * 4096;
    const __bf16* Vts = Vtsb + (kt & 1) * 4096;

    // fragment reads first (no vmem op may precede them)
    bf16x8 kf[2][4], vf[2][4];
#pragma unroll
    for (int t = 0; t < 2; ++t) {
      const int row = 32 * t + l32;
#pragma unroll
      for (int c = 0; c < 4; ++c)
        kf[t][c] = *(const bf16x8*)&Ks[row * 64 + (((2 * c + half) ^ (l32 & 7)) * 8)];
    }
#pragma unroll
    for (int v = 0; v < 2; ++v) {
      const int row = 32 * v + l32;
#pragma unroll
      for (int c = 0; c < 4; ++c)
        vf[v][c] = *(const bf16x8*)&Vts[row * 64 + (((2 * c + half) ^ (l32 & 7)) * 8)];
    }

    // prefetch next K/V tile (after the frag reads)
    if (kt + 1 < S / BKK) {
      __bf16* Kn = Ksb  + ((kt + 1) & 1) * 4096;
      __bf16* Vn = Vtsb + ((kt + 1) & 1) * 4096;
      const size_t kk1 = (size_t)(kt + 1) * BKK;
#pragma unroll
      for (int r2 = 0; r2 < 2; ++r2) {
        const int c = r2 * 256 + tid;
        const int r = c >> 3, cb = c & 7;
        const int cg = (cb ^ (r & 7)) * 8;
        load16_to_lds(Kp + (kk1 + r) * DH + cg, &Kn[c * 8]);
        load16_to_lds(Vp + (size_t)r * S + kk1 + cg, &Vn[c * 8]);
      }
    }

    // S'^T = K (Q*log2e/8)^T  -- scores already in exp2 domain
    f32x16 sa[2] = {};
#pragma unroll
    for (int t = 0; t < 2; ++t)
#pragma unroll
      for (int c = 0; c < 4; ++c)
        sa[t] = __builtin_amdgcn_mfma_f32_32x32x16_bf16(kf[t][c], qfB[c], sa[t], 0, 0, 0);

    float mx = -3.0e38f;
#pragma unroll
    for (int t = 0; t < 2; ++t)
#pragma unroll
      for (int r = 0; r < 16; ++r) mx = fmaxf(mx, sa[t][r]);
    mx = fmaxf(mx, __shfl_xor(mx, 32));
    const float mnew = fmaxf(mreg, mx);
    const float alpha = __builtin_amdgcn_exp2f(mreg - mnew);
    mreg = mnew;
    float sum = 0.0f;
#pragma unroll
    for (int t = 0; t < 2; ++t)
#pragma unroll
      for (int r = 0; r < 16; ++r) {
        const float p = __builtin_amdgcn_exp2f(sa[t][r] - mnew);
        sa[t][r] = p;
        sum += p;
      }
    sum += __shfl_xor(sum, 32);
    lreg = lreg * alpha + sum;
#pragma unroll
    for (int v = 0; v < 2; ++v)
#pragma unroll
      for (int r = 0; r < 16; ++r) oacc[v][r] *= alpha;

#pragma unroll
    for (int t = 0; t < 2; ++t)
#pragma unroll
      for (int g = 0; g < 4; ++g) {
        bf16x4 pv;
#pragma unroll
        for (int i = 0; i < 4; ++i) pv[i] = (__bf16)sa[t][4 * g + i];
        const int kc = 4 * t + g;
        *(bf16x4*)&Pb[l32 * 64 + ((kc ^ (l32 & 7)) * 8) + 4 * half] = pv;
      }

    bf16x8 pf[4];
#pragma unroll
    for (int c = 0; c < 4; ++c)
      pf[c] = *(const bf16x8*)&Pb[l32 * 64 + (((2 * c + half) ^ (l32 & 7)) * 8)];
#pragma unroll
    for (int v = 0; v < 2; ++v)
#pragma unroll
      for (int c = 0; c < 4; ++c)
        oacc[v] = __builtin_amdgcn_mfma_f32_32x32x16_bf16(vf[v][c], pf[c], oacc[v], 0, 0, 0);
  }

  const float linv = 1.0f / lreg;
#pragma unroll
  for (int v = 0; v < 2; ++v)
#pragma unroll
    for (int g = 0; g < 4; ++g) {
      bf16x4 ov;
#pragma unroll
      for (int i = 0; i < 4; ++i) ov[i] = (__bf16)(oacc[v][4 * g + i] * linv);
      const int dc = 4 * v + g;
      *(bf16x4*)&Pb[l32 * 64 + ((dc ^ (l32 & 7)) * 8) + 4 * half] = ov;
    }
#pragma unroll
  for (int cc = 0; cc < 4; ++cc) {
    const int c = cc * 64 + lane;
    const int r = c >> 3, g = c & 7;
    const bf16x8 od = *(const bf16x8*)&Pb[r * 64 + ((g ^ (r & 7)) * 8)];
    const int srow = qt * BQ + w * 32 + r;
    *(bf16x8*)&attn_o[((size_t)b * S + srow) * 1024 + h * 64 + g * 8] = od;
  }
}

// ---------------- launch ----------------
extern "C" void kernel_launch(void* const* d_in, const int* in_sizes, int n_in,
                              void* d_out, int out_size, void* d_ws, size_t ws_size,
                              hipStream_t stream) {
  const float* inputs = (const float*)d_in[0];
  const float* ln1_g  = (const float*)d_in[1];
  const float* ln1_b  = (const float*)d_in[2];
  const float* Wq     = (const float*)d_in[3];
  const float* Wk     = (const float*)d_in[4];
  const float* Wv     = (const float*)d_in[5];
  const float* Wo     = (const float*)d_in[6];
  const float* ln2_g  = (const float*)d_in[7];
  const float* ln2_b  = (const float*)d_in[8];
  const float* Wfc2   = (const float*)d_in[9];
  const float* bfc2   = (const float*)d_in[10];
  const float* Wfc3   = (const float*)d_in[11];
  const float* bfc3   = (const float*)d_in[12];
  float* out = (float*)d_out;
  char* ws = (char*)d_ws;
  const size_t MB = 1024 * 1024;

  __bf16* Wqkv_t = (__bf16*)(ws);            // 6 MB: [3072][1024]
  __bf16* Wo_t   = (__bf16*)(ws + 6 * MB);   // 2 MB
  __bf16* Wfc2_t = (__bf16*)(ws + 8 * MB);   // 8 MB: [4096][1024]
  __bf16* Wfc3_t = (__bf16*)(ws + 16 * MB);  // 8 MB: [1024][4096]
  __bf16* xb     = (__bf16*)(ws + 24 * MB);  // 8 MB; reused as attn_o
  __bf16* attn_o = xb;
  __bf16* qkv    = (__bf16*)(ws + 32 * MB);  // 24 MB; reused:
  float*  mlp_in = (float*)(ws + 32 * MB);   //   16 MB
  __bf16* h2     = (__bf16*)(ws + 48 * MB);  //   8 MB
  __bf16* qrb    = (__bf16*)(ws + 56 * MB);  // 8 MB; qr/kr/vt reused as hbuf
  __bf16* krb    = (__bf16*)(ws + 64 * MB);
  __bf16* vtb    = (__bf16*)(ws + 72 * MB);
  __bf16* hbuf   = (__bf16*)(ws + 56 * MB);  // 32 MB (after attention)

  const dim3 tb(32, 8);
  transpose_cast_qkv<<<dim3(32, 32, 3), tb, 0, stream>>>(Wq, Wk, Wv, Wqkv_t);
  transpose_cast<<<dim3(32, 32),  tb, 0, stream>>>(Wo,   Wo_t,   1024, 1024);
  transpose_cast<<<dim3(128, 32), tb, 0, stream>>>(Wfc2, Wfc2_t, 1024, 4096);
  transpose_cast<<<dim3(32, 128), tb, 0, stream>>>(Wfc3, Wfc3_t, 4096, 1024);

  ln_kernel<<<4096, 256, 0, stream>>>(inputs, ln1_g, ln1_b, xb);

  gemm_bf16<128, 32, EPI_BF16><<<dim3(24, 32), 256, 0, stream>>>(
      xb, Wqkv_t, qkv, nullptr, nullptr, nullptr, 4096, 3072, 1024);

  rope_qk<<<8192, 256, 0, stream>>>(qkv, qrb, krb);
  v_transpose<<<dim3(32, 16, 2), 256, 0, stream>>>(qkv, vtb);

  attn_kernel<<<dim3(16, 16, 2), 256, 0, stream>>>(qrb, krb, vtb, attn_o);

  gemm_bf16<64, 64, EPI_RES_F32><<<dim3(8, 64), 256, 0, stream>>>(
      attn_o, Wo_t, nullptr, mlp_in, nullptr, inputs, 4096, 1024, 1024);

  ln_kernel<<<4096, 256, 0, stream>>>(mlp_in, ln2_g, ln2_b, h2);

  gemm_bf16<128, 32, EPI_GELU_BF16><<<dim3(32, 32), 256, 0, stream>>>(
      h2, Wfc2_t, hbuf, nullptr, bfc2, nullptr, 4096, 4096, 1024);

  gemm_bf16<64, 64, EPI_BIAS_RES_F32><<<dim3(8, 64), 256, 0, stream>>>(
      hbuf, Wfc3_t, nullptr, out, bfc3, mlp_in, 4096, 1024, 4096);
}

// Round 11
// 346.284 us; speedup vs baseline: 1.1660x; 1.0114x over previous
//
#include <hip/hip_runtime.h>
#include <cstdint>
#include <cstddef>

// ---------------- common types / helpers ----------------
typedef __bf16 bf16x8 __attribute__((ext_vector_type(8)));
typedef __bf16 bf16x4 __attribute__((ext_vector_type(4)));
typedef float  f32x4  __attribute__((ext_vector_type(4)));
typedef float  f32x16 __attribute__((ext_vector_type(16)));

__device__ __forceinline__ void load16_to_lds(const void* g, void* l) {
  __builtin_amdgcn_global_load_lds(
      (const __attribute__((address_space(1))) void*)g,
      (__attribute__((address_space(3))) void*)l, 16, 0, 0);
}

// ---------------- weight cast+transpose: f32 (K,N) -> bf16 (N,K) ----------------
__global__ __launch_bounds__(256) void transpose_cast(
    const float* __restrict__ src, __bf16* __restrict__ dst, int K, int N)
{
  __shared__ float tile[32][33];
  const int n0 = blockIdx.x * 32, k0 = blockIdx.y * 32;
  const int tx = threadIdx.x, ty = threadIdx.y; // (32,8)
#pragma unroll
  for (int i = 0; i < 32; i += 8)
    tile[ty + i][tx] = src[(size_t)(k0 + ty + i) * N + n0 + tx];
  __syncthreads();
#pragma unroll
  for (int i = 0; i < 32; i += 8)
    dst[(size_t)(n0 + ty + i) * K + k0 + tx] = (__bf16)tile[tx][ty + i];
}

// 3x 1024x1024 in one launch (z picks the weight)
__global__ __launch_bounds__(256) void transpose_cast_qkv(
    const float* __restrict__ s0, const float* __restrict__ s1,
    const float* __restrict__ s2, __bf16* __restrict__ dst)
{
  __shared__ float tile[32][33];
  const float* src = blockIdx.z == 0 ? s0 : blockIdx.z == 1 ? s1 : s2;
  __bf16* d = dst + (size_t)blockIdx.z * 1024 * 1024;
  const int n0 = blockIdx.x * 32, k0 = blockIdx.y * 32;
  const int tx = threadIdx.x, ty = threadIdx.y; // (32,8)
#pragma unroll
  for (int i = 0; i < 32; i += 8)
    tile[ty + i][tx] = src[(size_t)(k0 + ty + i) * 1024 + n0 + tx];
  __syncthreads();
#pragma unroll
  for (int i = 0; i < 32; i += 8)
    d[(size_t)(n0 + ty + i) * 1024 + k0 + tx] = (__bf16)tile[tx][ty + i];
}

// ---------------- LayerNorm: f32 row(1024) -> bf16 ----------------
__global__ __launch_bounds__(256) void ln_kernel(
    const float* __restrict__ x, const float* __restrict__ g,
    const float* __restrict__ bta, __bf16* __restrict__ out)
{
  const int row = blockIdx.x;
  const int t = threadIdx.x;
  const float4 v = ((const float4*)(x + (size_t)row * 1024))[t];
  float s  = v.x + v.y + v.z + v.w;
  float ss = v.x * v.x + v.y * v.y + v.z * v.z + v.w * v.w;
#pragma unroll
  for (int o = 32; o > 0; o >>= 1) { s += __shfl_down(s, o); ss += __shfl_down(ss, o); }
  __shared__ float rs[4], rss[4];
  const int w = t >> 6, l = t & 63;
  if (l == 0) { rs[w] = s; rss[w] = ss; }
  __syncthreads();
  s  = rs[0] + rs[1] + rs[2] + rs[3];
  ss = rss[0] + rss[1] + rss[2] + rss[3];
  const float mu = s * (1.0f / 1024.0f);
  const float var = ss * (1.0f / 1024.0f) - mu * mu;
  const float rstd = rsqrtf(var + 1e-5f);
  const float4 gg = ((const float4*)g)[t];
  const float4 bb = ((const float4*)bta)[t];
  __bf16* o = out + (size_t)row * 1024 + t * 4;
  o[0] = (__bf16)((v.x - mu) * rstd * gg.x + bb.x);
  o[1] = (__bf16)((v.y - mu) * rstd * gg.y + bb.y);
  o[2] = (__bf16)((v.z - mu) * rstd * gg.z + bb.z);
  o[3] = (__bf16)((v.w - mu) * rstd * gg.w + bb.w);
}

// ---------------- bf16 MFMA GEMM: C = A(MxK) * Bt(NxK)^T ----------------
// STATIC double-buffer (As0/As1/Bs0/Bs1 are SEPARATE __shared__ arrays) +
// manual 2x K-loop unroll with constant buffer parity + PREFETCH-FIRST.
// Round-8's prefetch-first failed because As[1-p] (runtime p) defeated alias
// analysis -> compiler inserted vmcnt(0) before the ds_reads. With distinct
// LDS objects the disjointness is provable: the prefetch gets a full
// iteration (~400-600cy) of flight before the next barrier's drain, while
// ds_reads proceed un-gated. One barrier per staged tile, as before.
// KB=64 (Wo/FC3): half the barriers; XOR chunk swizzle for 128B rows.
enum { EPI_BF16 = 0, EPI_RES_F32 = 1, EPI_GELU_BF16 = 2, EPI_BIAS_RES_F32 = 3 };

template <int TM, int KB, int EPI>
__global__ __launch_bounds__(256, 2) void gemm_bf16(
    const __bf16* __restrict__ A, const __bf16* __restrict__ Bt,
    __bf16* __restrict__ outb, float* __restrict__ outf,
    const float* __restrict__ bias, const float* __restrict__ res,
    int M, int N, int K)
{
  constexpr int MT = TM / 32;           // mt tiles per wave
  constexpr int KS = KB / 32;           // k-substeps per staged tile
  __shared__ __bf16 As0[TM * KB], As1[TM * KB];
  __shared__ __bf16 Bs0[128 * KB], Bs1[128 * KB];
  const int tid  = threadIdx.x;
  const int lane = tid & 63, w = tid >> 6;
  const int wm = w >> 1, wn = w & 1;
  const int quad = lane >> 4, l16 = lane & 15;
  const int m0 = blockIdx.y * TM, n0 = blockIdx.x * 128;

  f32x4 acc[MT][4] = {};
  const __bf16* Ag = A  + (size_t)m0 * K;
  const __bf16* Bg = Bt + (size_t)n0 * K;

#define G_STAGE(AsX, BsX, k0) {                                            \
    _Pragma("unroll")                                                      \
    for (int r2 = 0; r2 < TM * KB / 2048; ++r2) {                          \
      const int c = r2 * 256 + tid;                                        \
      const int r = c / (KB / 8), cb = c % (KB / 8);                       \
      const int g = (KB == 64) ? (cb ^ (r & 7)) : cb;                      \
      load16_to_lds(Ag + (size_t)r * K + (k0) + g * 8, &AsX[c * 8]);       \
    }                                                                      \
    _Pragma("unroll")                                                      \
    for (int r2 = 0; r2 < KB / 16; ++r2) {                                 \
      const int c = r2 * 256 + tid;                                        \
      const int r = c / (KB / 8), cb = c % (KB / 8);                       \
      const int g = (KB == 64) ? (cb ^ (r & 7)) : cb;                      \
      load16_to_lds(Bg + (size_t)r * K + (k0) + g * 8, &BsX[c * 8]);       \
    } }

#define G_COMPUTE(AsX, BsX) {                                              \
    bf16x8 af[MT][KS], bfr[4][KS];                                         \
    _Pragma("unroll")                                                      \
    for (int mt = 0; mt < MT; ++mt) {                                      \
      const int row = wm * (TM / 2) + mt * 16 + l16;                       \
      _Pragma("unroll")                                                    \
      for (int ks = 0; ks < KS; ++ks) {                                    \
        const int ch = (KB == 64) ? ((ks * 4 + quad) ^ (row & 7)) : quad;  \
        af[mt][ks] = *(const bf16x8*)&AsX[row * KB + ch * 8];              \
      }                                                                    \
    }                                                                      \
    _Pragma("unroll")                                                      \
    for (int nt = 0; nt < 4; ++nt) {                                       \
      const int row = wn * 64 + nt * 16 + l16;                             \
      _Pragma("unroll")                                                    \
      for (int ks = 0; ks < KS; ++ks) {                                    \
        const int ch = (KB == 64) ? ((ks * 4 + quad) ^ (row & 7)) : quad;  \
        bfr[nt][ks] = *(const bf16x8*)&BsX[row * KB + ch * 8];             \
      }                                                                    \
    }                                                                      \
    _Pragma("unroll")                                                      \
    for (int ks = 0; ks < KS; ++ks)                                        \
      _Pragma("unroll")                                                    \
      for (int mt = 0; mt < MT; ++mt)                                      \
        _Pragma("unroll")                                                  \
        for (int nt = 0; nt < 4; ++nt)                                     \
          acc[mt][nt] = __builtin_amdgcn_mfma_f32_16x16x32_bf16(           \
              af[mt][ks], bfr[nt][ks], acc[mt][nt], 0, 0, 0);              \
  }

  G_STAGE(As0, Bs0, 0);
  const int nk = K / KB;               // even at every call site (32/16/64)
  for (int kt = 0; kt < nk; kt += 2) {
    __syncthreads();                   // drains prefetch into buf0
    if (kt + 1 < nk) G_STAGE(As1, Bs1, (kt + 1) * KB);   // prefetch FIRST
    G_COMPUTE(As0, Bs0);
    __syncthreads();                   // drains prefetch into buf1
    if (kt + 2 < nk) G_STAGE(As0, Bs0, (kt + 2) * KB);
    G_COMPUTE(As1, Bs1);
  }
#undef G_STAGE
#undef G_COMPUTE

#pragma unroll
  for (int mt = 0; mt < MT; ++mt) {
#pragma unroll
    for (int nt = 0; nt < 4; ++nt) {
      const int col = n0 + wn * 64 + nt * 16 + l16;
#pragma unroll
      for (int i = 0; i < 4; ++i) {
        const int row = m0 + wm * (TM / 2) + mt * 16 + quad * 4 + i;
        float v = acc[mt][nt][i];
        const size_t idx = (size_t)row * N + col;
        if (EPI == EPI_BF16) {
          outb[idx] = (__bf16)v;
        } else if (EPI == EPI_RES_F32) {
          outf[idx] = v + res[idx];
        } else if (EPI == EPI_GELU_BF16) {
          v += bias[col];
          outb[idx] = (__bf16)(0.5f * v * (1.0f + erff(v * 0.70710678118f)));
        } else {
          v += bias[col];
          outf[idx] = v + res[idx];
        }
      }
    }
  }
}

// ---------------- RoPE for q,k: qkv(4096x3072) -> qr,kr [b][h][s][d] --------
// Q pre-scaled by 0.125*log2(e): scores land in the exp2 domain.
__global__ __launch_bounds__(256) void rope_qk(
    const __bf16* __restrict__ qkv, __bf16* __restrict__ qr, __bf16* __restrict__ kr)
{
  const int idx = blockIdx.x * 256 + threadIdx.x; // (b,s,h,d2)
  const int d2 = idx & 31;
  const int h  = (idx >> 5) & 15;
  const int bs = idx >> 9;       // b*2048+s
  const int s  = bs & 2047;
  const int b  = bs >> 11;
  const float inv_freq = exp2f(-((float)d2 * (1.0f / 32.0f)) * 13.2877123795f); // log2(1e4)
  const float ang = (float)s * inv_freq;
  const float c = cosf(ang), sn = sinf(ang);
  const float QS = 0.125f * 1.44269504f;  // (1/sqrt(64)) * log2(e)
  const __bf16* qp = qkv + (size_t)bs * 3072 + h * 64 + 2 * d2;
  const __bf16* kp = qp + 1024;
  const float q0 = (float)qp[0], q1 = (float)qp[1];
  const float k0 = (float)kp[0], k1 = (float)kp[1];
  const size_t o = ((size_t)(b * 16 + h) * 2048 + s) * 64 + 2 * d2;
  qr[o]     = (__bf16)((q0 * c - q1 * sn) * QS);
  qr[o + 1] = (__bf16)((q1 * c + q0 * sn) * QS);
  kr[o]     = (__bf16)(k0 * c - k1 * sn);
  kr[o + 1] = (__bf16)(k1 * c + k0 * sn);
}

// ---------------- V transpose: qkv v-cols -> vt [b][h][d][s] ----------------
__global__ __launch_bounds__(256) void v_transpose(
    const __bf16* __restrict__ qkv, __bf16* __restrict__ vt)
{
  __shared__ __bf16 t[64][72];
  const int st = blockIdx.x, h = blockIdx.y, b = blockIdx.z;
  const int tx = threadIdx.x & 63, ty = threadIdx.x >> 6; // 64x4
  const int s0 = st * 64;
  const __bf16* src = qkv + ((size_t)(b * 2048 + s0)) * 3072 + 2048 + h * 64;
#pragma unroll
  for (int i = 0; i < 64; i += 4)
    t[ty + i][tx] = src[(size_t)(ty + i) * 3072 + tx];
  __syncthreads();
  __bf16* dst = vt + ((size_t)(b * 16 + h) * 64) * 2048 + s0;
#pragma unroll
  for (int i = 0; i < 64; i += 4)
    dst[(size_t)(ty + i) * 2048 + tx] = t[tx][ty + i];
}

// ---------------- flash attention v7: static dbuf + prefetch-first ----------
// Same static-buffer trick as the GEMM: Ks0/Ks1/Vts0/Vts1 are separate
// __shared__ arrays, K-loop unrolled 2x with constant parity, prefetch
// issued FIRST after each barrier. Pb lives in Qs (statically distinct from
// the K/V buffers, wave-local rows -> no extra barrier). exp2-domain softmax
// with bare v_exp (__builtin_amdgcn_exp2f; exp2f's libm fixup cost +10us, r9).
__global__ __launch_bounds__(256, 2) void attn_kernel(
    const __bf16* __restrict__ qr, const __bf16* __restrict__ kr,
    const __bf16* __restrict__ vt, __bf16* __restrict__ attn_o)
{
  constexpr int S = 2048, DH = 64, NH = 16, BQ = 128, BKK = 64;
  __shared__ __align__(16) __bf16 Qs[BQ * 64];           // swizzled; per-wave Pb
  __shared__ __align__(16) __bf16 Ks0[64 * 64], Ks1[64 * 64];
  __shared__ __align__(16) __bf16 Vts0[64 * 64], Vts1[64 * 64];

  const int tid = threadIdx.x;
  const int lane = tid & 63, w = tid >> 6;
  const int l32 = lane & 31, half = lane >> 5;
  const int qt = blockIdx.x, h = blockIdx.y, b = blockIdx.z;
  const int bh = b * NH + h;
  const __bf16* Q  = qr + ((size_t)bh * S + qt * BQ) * DH;
  const __bf16* Kp = kr + (size_t)bh * S * DH;
  const __bf16* Vp = vt + (size_t)bh * DH * S;
  __bf16* Pb = Qs + w * 2048;                // wave-local [32][64] swizzled

#define A_STAGE(KsX, VtsX, kk) {                                           \
    _Pragma("unroll")                                                      \
    for (int r2 = 0; r2 < 2; ++r2) {                                       \
      const int c = r2 * 256 + tid;                                        \
      const int r = c >> 3, cb = c & 7;                                    \
      const int cg = (cb ^ (r & 7)) * 8;                                   \
      load16_to_lds(Kp + (size_t)((kk) + r) * DH + cg, &KsX[c * 8]);       \
      load16_to_lds(Vp + (size_t)r * S + (kk) + cg, &VtsX[c * 8]);         \
    } }

  // initial stage: Q + tile 0
#pragma unroll
  for (int r4 = 0; r4 < 4; ++r4) {
    const int c = r4 * 256 + tid;
    const int r = c >> 3, cb = c & 7;
    load16_to_lds(Q + (size_t)r * DH + ((cb ^ (r & 7)) * 8), &Qs[c * 8]);
  }
  A_STAGE(Ks0, Vts0, 0);
  __syncthreads();

  bf16x8 qfB[4];
  {
    const int row = w * 32 + l32;
#pragma unroll
    for (int c = 0; c < 4; ++c)
      qfB[c] = *(const bf16x8*)&Qs[row * 64 + (((2 * c + half) ^ (row & 7)) * 8)];
  }

  float mreg = -3.0e38f, lreg = 0.0f;
  f32x16 oacc[2] = {};

#define A_COMPUTE(KsX, VtsX) {                                             \
    bf16x8 kf[2][4], vf[2][4];                                             \
    _Pragma("unroll")                                                      \
    for (int t = 0; t < 2; ++t) {                                          \
      const int row = 32 * t + l32;                                        \
      _Pragma("unroll")                                                    \
      for (int c = 0; c < 4; ++c)                                          \
        kf[t][c] = *(const bf16x8*)&KsX[row * 64 + (((2 * c + half) ^ (l32 & 7)) * 8)]; \
    }                                                                      \
    _Pragma("unroll")                                                      \
    for (int v = 0; v < 2; ++v) {                                          \
      const int row = 32 * v + l32;                                        \
      _Pragma("unroll")                                                    \
      for (int c = 0; c < 4; ++c)                                          \
        vf[v][c] = *(const bf16x8*)&VtsX[row * 64 + (((2 * c + half) ^ (l32 & 7)) * 8)]; \
    }                                                                      \
    f32x16 sa[2] = {};                                                     \
    _Pragma("unroll")                                                      \
    for (int t = 0; t < 2; ++t)                                            \
      _Pragma("unroll")                                                    \
      for (int c = 0; c < 4; ++c)                                          \
        sa[t] = __builtin_amdgcn_mfma_f32_32x32x16_bf16(kf[t][c], qfB[c], sa[t], 0, 0, 0); \
    float mx = -3.0e38f;                                                   \
    _Pragma("unroll")                                                      \
    for (int t = 0; t < 2; ++t)                                            \
      _Pragma("unroll")                                                    \
      for (int r = 0; r < 16; ++r) mx = fmaxf(mx, sa[t][r]);               \
    mx = fmaxf(mx, __shfl_xor(mx, 32));                                    \
    const float mnew = fmaxf(mreg, mx);                                    \
    const float alpha = __builtin_amdgcn_exp2f(mreg - mnew);               \
    mreg = mnew;                                                           \
    float sum = 0.0f;                                                      \
    _Pragma("unroll")                                                      \
    for (int t = 0; t < 2; ++t)                                            \
      _Pragma("unroll")                                                    \
      for (int r = 0; r < 16; ++r) {                                       \
        const float p = __builtin_amdgcn_exp2f(sa[t][r] - mnew);           \
        sa[t][r] = p;                                                      \
        sum += p;                                                          \
      }                                                                    \
    sum += __shfl_xor(sum, 32);                                            \
    lreg = lreg * alpha + sum;                                             \
    _Pragma("unroll")                                                      \
    for (int v = 0; v < 2; ++v)                                            \
      _Pragma("unroll")                                                    \
      for (int r = 0; r < 16; ++r) oacc[v][r] *= alpha;                    \
    _Pragma("unroll")                                                      \
    for (int t = 0; t < 2; ++t)                                            \
      _Pragma("unroll")                                                    \
      for (int g = 0; g < 4; ++g) {                                        \
        bf16x4 pv;                                                         \
        _Pragma("unroll")                                                  \
        for (int i = 0; i < 4; ++i) pv[i] = (__bf16)sa[t][4 * g + i];      \
        const int kc = 4 * t + g;                                          \
        *(bf16x4*)&Pb[l32 * 64 + ((kc ^ (l32 & 7)) * 8) + 4 * half] = pv;  \
      }                                                                    \
    bf16x8 pf[4];                                                          \
    _Pragma("unroll")                                                      \
    for (int c = 0; c < 4; ++c)                                            \
      pf[c] = *(const bf16x8*)&Pb[l32 * 64 + (((2 * c + half) ^ (l32 & 7)) * 8)]; \
    _Pragma("unroll")                                                      \
    for (int v = 0; v < 2; ++v)                                            \
      _Pragma("unroll")                                                    \
      for (int c = 0; c < 4; ++c)                                          \
        oacc[v] = __builtin_amdgcn_mfma_f32_32x32x16_bf16(vf[v][c], pf[c], oacc[v], 0, 0, 0); \
  }

  for (int kt = 0; kt < S / BKK; kt += 2) {
    __syncthreads();                       // drains prefetch into buf0
    if (kt + 1 < S / BKK) A_STAGE(Ks1, Vts1, (kt + 1) * BKK);  // prefetch FIRST
    A_COMPUTE(Ks0, Vts0);
    __syncthreads();                       // drains prefetch into buf1
    if (kt + 2 < S / BKK) A_STAGE(Ks0, Vts0, (kt + 2) * BKK);
    A_COMPUTE(Ks1, Vts1);
  }
#undef A_STAGE
#undef A_COMPUTE

  const float linv = 1.0f / lreg;
#pragma unroll
  for (int v = 0; v < 2; ++v)
#pragma unroll
    for (int g = 0; g < 4; ++g) {
      bf16x4 ov;
#pragma unroll
      for (int i = 0; i < 4; ++i) ov[i] = (__bf16)(oacc[v][4 * g + i] * linv);
      const int dc = 4 * v + g;
      *(bf16x4*)&Pb[l32 * 64 + ((dc ^ (l32 & 7)) * 8) + 4 * half] = ov;
    }
#pragma unroll
  for (int cc = 0; cc < 4; ++cc) {
    const int c = cc * 64 + lane;
    const int r = c >> 3, g = c & 7;
    const bf16x8 od = *(const bf16x8*)&Pb[r * 64 + ((g ^ (r & 7)) * 8)];
    const int srow = qt * BQ + w * 32 + r;
    *(bf16x8*)&attn_o[((size_t)b * S + srow) * 1024 + h * 64 + g * 8] = od;
  }
}

// ---------------- launch ----------------
extern "C" void kernel_launch(void* const* d_in, const int* in_sizes, int n_in,
                              void* d_out, int out_size, void* d_ws, size_t ws_size,
                              hipStream_t stream) {
  const float* inputs = (const float*)d_in[0];
  const float* ln1_g  = (const float*)d_in[1];
  const float* ln1_b  = (const float*)d_in[2];
  const float* Wq     = (const float*)d_in[3];
  const float* Wk     = (const float*)d_in[4];
  const float* Wv     = (const float*)d_in[5];
  const float* Wo     = (const float*)d_in[6];
  const float* ln2_g  = (const float*)d_in[7];
  const float* ln2_b  = (const float*)d_in[8];
  const float* Wfc2   = (const float*)d_in[9];
  const float* bfc2   = (const float*)d_in[10];
  const float* Wfc3   = (const float*)d_in[11];
  const float* bfc3   = (const float*)d_in[12];
  float* out = (float*)d_out;
  char* ws = (char*)d_ws;
  const size_t MB = 1024 * 1024;

  __bf16* Wqkv_t = (__bf16*)(ws);            // 6 MB: [3072][1024]
  __bf16* Wo_t   = (__bf16*)(ws + 6 * MB);   // 2 MB
  __bf16* Wfc2_t = (__bf16*)(ws + 8 * MB);   // 8 MB: [4096][1024]
  __bf16* Wfc3_t = (__bf16*)(ws + 16 * MB);  // 8 MB: [1024][4096]
  __bf16* xb     = (__bf16*)(ws + 24 * MB);  // 8 MB; reused as attn_o
  __bf16* attn_o = xb;
  __bf16* qkv    = (__bf16*)(ws + 32 * MB);  // 24 MB; reused:
  float*  mlp_in = (float*)(ws + 32 * MB);   //   16 MB
  __bf16* h2     = (__bf16*)(ws + 48 * MB);  //   8 MB
  __bf16* qrb    = (__bf16*)(ws + 56 * MB);  // 8 MB; qr/kr/vt reused as hbuf
  __bf16* krb    = (__bf16*)(ws + 64 * MB);
  __bf16* vtb    = (__bf16*)(ws + 72 * MB);
  __bf16* hbuf   = (__bf16*)(ws + 56 * MB);  // 32 MB (after attention)

  const dim3 tb(32, 8);
  transpose_cast_qkv<<<dim3(32, 32, 3), tb, 0, stream>>>(Wq, Wk, Wv, Wqkv_t);
  transpose_cast<<<dim3(32, 32),  tb, 0, stream>>>(Wo,   Wo_t,   1024, 1024);
  transpose_cast<<<dim3(128, 32), tb, 0, stream>>>(Wfc2, Wfc2_t, 1024, 4096);
  transpose_cast<<<dim3(32, 128), tb, 0, stream>>>(Wfc3, Wfc3_t, 4096, 1024);

  ln_kernel<<<4096, 256, 0, stream>>>(inputs, ln1_g, ln1_b, xb);

  gemm_bf16<128, 32, EPI_BF16><<<dim3(24, 32), 256, 0, stream>>>(
      xb, Wqkv_t, qkv, nullptr, nullptr, nullptr, 4096, 3072, 1024);

  rope_qk<<<8192, 256, 0, stream>>>(qkv, qrb, krb);
  v_transpose<<<dim3(32, 16, 2), 256, 0, stream>>>(qkv, vtb);

  attn_kernel<<<dim3(16, 16, 2), 256, 0, stream>>>(qrb, krb, vtb, attn_o);

  gemm_bf16<64, 64, EPI_RES_F32><<<dim3(8, 64), 256, 0, stream>>>(
      attn_o, Wo_t, nullptr, mlp_in, nullptr, inputs, 4096, 1024, 1024);

  ln_kernel<<<4096, 256, 0, stream>>>(mlp_in, ln2_g, ln2_b, h2);

  gemm_bf16<128, 32, EPI_GELU_BF16><<<dim3(32, 32), 256, 0, stream>>>(
      h2, Wfc2_t, hbuf, nullptr, bfc2, nullptr, 4096, 4096, 1024);

  gemm_bf16<64, 64, EPI_BIAS_RES_F32><<<dim3(8, 64), 256, 0, stream>>>(
      hbuf, Wfc3_t, nullptr, out, bfc3, mlp_in, 4096, 1024, 4096);
}